// Round 1
// baseline (176.676 us; speedup 1.0000x reference)
//
#include <hip/hip_runtime.h>

// FeatureExpansion: per (b, ol) stride of 10x32 f32 -> 1120 f32 outputs
// [std(32) | z(32) | ld(32) | ret(32) | covf(496) | corrf(496)]
// One wave (64 lanes) per stride; 4 waves (strides) per 256-thread block.

constexpr int S      = 10;
constexpr int F      = 32;
constexpr int NPAIR  = 496;     // F*(F-1)/2
constexpr int OUTW   = 1120;    // 4*F + 2*NPAIR
constexpr int WAVES  = 4;
// per-wave LDS slice (floats): raw/ms[320] | mean[32] | stdv[32] | stage[1120]
constexpr int SLICE  = 320 + 32 + 32 + OUTW;   // 1504 floats = 6016 B (16B aligned)

__global__ __launch_bounds__(256, 4)
void fe_kernel(const float* __restrict__ in, float* __restrict__ out, int nstrides)
{
    __shared__ float lds[WAVES * SLICE];

    const int wv   = threadIdx.x >> 6;
    const int lane = threadIdx.x & 63;
    int sid = blockIdx.x * WAVES + wv;
    if (sid >= nstrides) sid = nstrides - 1;   // clamp (grid divides exactly for this shape)

    float* raw   = &lds[wv * SLICE];   // 320 floats, becomes mean-subtracted in place
    float* mean  = raw + 320;          // 32
    float* stdv  = raw + 352;          // 32
    float* stage = raw + 384;          // 1120

    const float* src = in + (size_t)sid * (S * F);

    // ---- 1. global -> LDS (two float4 loads per wave-slot, fully coalesced) ----
    {
        float4 v0 = *(const float4*)(src + 4 * lane);
        *(float4*)(raw + 4 * lane) = v0;
        if (lane < 16) {
            float4 v1 = *(const float4*)(src + 256 + 4 * lane);
            *(float4*)(raw + 256 + 4 * lane) = v1;
        }
    }
    __syncthreads();

    const int f    = lane & 31;
    const int half = lane >> 5;

    // ---- 2. shared reduction pass: mean (half 0) and linear-decay/return (half 1) ----
    float meanf = 0.f;
    {
        float sum = 0.f, ldacc = 0.f, first = 0.f, last = 0.f;
        #pragma unroll
        for (int s = 0; s < S; ++s) {
            float v = raw[s * F + f];
            sum += v;
            ldacc += (float)(s + 1) * v;
            if (s == 0)     first = v;
            if (s == S - 1) last  = v;
        }
        if (half == 0) {
            meanf = sum * (1.0f / (float)S);
            mean[f] = meanf;
        } else {
            stage[2 * F + f] = ldacc * (1.0f / 55.0f);            // linspace(1,10)/55
            float ret = (first == 0.0f) ? 0.0f : (last / first);  // divide_no_nan
            stage[3 * F + f] = ret - 1.0f;
        }
    }
    __syncthreads();

    // ---- 3. mean-subtract in place (lane handles feature f at s = half + 2k) ----
    {
        float mf = mean[f];
        #pragma unroll
        for (int k = 0; k < 5; ++k) {
            int idx = lane + 64 * k;     // idx % 32 == f
            raw[idx] -= mf;
        }
    }
    __syncthreads();

    // ---- 4. variance/std/z (half 0 lanes) ----
    if (half == 0) {
        float ss = 0.f;
        #pragma unroll
        for (int s = 0; s < S; ++s) {
            float d = raw[s * F + f];
            ss += d * d;
        }
        float var = ss * (1.0f / (float)S);    // biased variance
        float sd  = sqrtf(var);
        stdv[f]      = sd;
        stage[f]     = sd;
        stage[F + f] = (sd == 0.0f) ? 0.0f : (meanf / sd);   // z = divide_no_nan(mean, std)
    }
    __syncthreads();

    // ---- 5. pairwise products: 32x32 = 8x8 lane grid of 4x4 register tiles ----
    {
        const int rb = lane >> 3;   // 0..7
        const int cb = lane & 7;    // 0..7
        float acc[4][4];
        #pragma unroll
        for (int i = 0; i < 4; ++i)
            #pragma unroll
            for (int j = 0; j < 4; ++j) acc[i][j] = 0.f;

        #pragma unroll
        for (int s = 0; s < S; ++s) {
            float4 a4 = *(float4*)(raw + s * F + 4 * rb);   // ds_read_b128, broadcast-friendly
            float4 b4 = *(float4*)(raw + s * F + 4 * cb);
            const float aa[4] = {a4.x, a4.y, a4.z, a4.w};
            const float bb[4] = {b4.x, b4.y, b4.z, b4.w};
            #pragma unroll
            for (int i = 0; i < 4; ++i)
                #pragma unroll
                for (int j = 0; j < 4; ++j)
                    acc[i][j] += aa[i] * bb[j];
        }

        float4 sa4 = *(float4*)(stdv + 4 * rb);
        float4 sb4 = *(float4*)(stdv + 4 * cb);
        const float sa[4] = {sa4.x, sa4.y, sa4.z, sa4.w};
        const float sb[4] = {sb4.x, sb4.y, sb4.z, sb4.w};

        #pragma unroll
        for (int i = 0; i < 4; ++i) {
            const int r = 4 * rb + i;
            #pragma unroll
            for (int j = 0; j < 4; ++j) {
                const int c = 4 * cb + j;
                if (r > c) {                       // strict lower triangle
                    const int p = (r * (r - 1)) / 2 + c;
                    float prod = acc[i][j];
                    stage[4 * F + p]         = prod * (1.0f / 9.0f);   // cov: /(S-1)
                    float den = sa[i] * sb[j];
                    stage[4 * F + NPAIR + p] = (den == 0.0f) ? 0.0f
                                               : (prod * (1.0f / (float)S)) / den; // corr
                }
            }
        }
    }
    __syncthreads();

    // ---- 6. coalesced writeout: 280 float4 per stride ----
    {
        float* dst = out + (size_t)sid * OUTW;
        #pragma unroll
        for (int k = 0; k < 5; ++k) {
            int idx4 = lane + 64 * k;
            if (idx4 < OUTW / 4) {
                *(float4*)(dst + 4 * idx4) = *(float4*)(stage + 4 * idx4);
            }
        }
    }
}

extern "C" void kernel_launch(void* const* d_in, const int* in_sizes, int n_in,
                              void* d_out, int out_size, void* d_ws, size_t ws_size,
                              hipStream_t stream)
{
    const float* in = (const float*)d_in[0];
    float* out      = (float*)d_out;
    const int nstrides = in_sizes[0] / (S * F);          // 122880 for (2048,600,32)
    const int grid     = (nstrides + WAVES - 1) / WAVES; // 30720
    fe_kernel<<<grid, 256, 0, stream>>>(in, out, nstrides);
}

// Round 3
// 150.146 us; speedup vs baseline: 1.1767x; 1.1767x over previous
//
#include <hip/hip_runtime.h>

// FeatureExpansion: per (b, ol) stride of 10x32 f32 -> 1120 f32 outputs
// [std(32) | z(32) | ld(32) | ret(32) | covf(496) | corrf(496)]
// One wave (64 lanes) per stride; 4 waves (strides) per 256-thread block.
// Waves are fully independent: wave-local sync only (no s_barrier).

typedef float fx4 __attribute__((ext_vector_type(4)));   // native vector: OK for nontemporal builtins

constexpr int S      = 10;
constexpr int F      = 32;
constexpr int NPAIR  = 496;     // F*(F-1)/2
constexpr int OUTW   = 1120;    // 4*F + 2*NPAIR
constexpr int WAVES  = 4;
// per-wave LDS slice (floats): raw/ms[320] | stage[1120]
// stage[0:32]=std  stage[32:64]=mean->z  stage[64:96]=ld  stage[96:128]=ret
constexpr int SLICE  = 320 + OUTW;   // 1440 floats = 5760 B

// Wave-local barrier: all of this wave's LDS ops complete + compiler/sched fence.
// Legal replacement for __syncthreads() because each wave touches only its own
// LDS slice; lanes of one wave share a program counter.
__device__ __forceinline__ void wave_sync() {
    asm volatile("s_waitcnt lgkmcnt(0)" ::: "memory");
    __builtin_amdgcn_sched_barrier(0);
}

__device__ __forceinline__ float fast_rcp(float x) {
    return __builtin_amdgcn_rcpf(x);
}

__global__ __launch_bounds__(256, 4)
void fe_kernel(const float* __restrict__ in, float* __restrict__ out, int nstrides)
{
    __shared__ float lds[WAVES * SLICE];

    const int wv   = threadIdx.x >> 6;
    const int lane = threadIdx.x & 63;
    int sid = blockIdx.x * WAVES + wv;
    if (sid >= nstrides) sid = nstrides - 1;   // clamp (grid divides exactly here)

    float* raw   = &lds[wv * SLICE];   // 320 floats, becomes mean-subtracted in place
    float* stage = raw + 320;          // 1120

    const float* src = in + (size_t)sid * (S * F);

    // ---- 1. global -> LDS (streamed, read-once) ----
    {
        fx4 v0 = __builtin_nontemporal_load((const fx4*)(src + 4 * lane));
        *(fx4*)(raw + 4 * lane) = v0;
        if (lane < 16) {
            fx4 v1 = __builtin_nontemporal_load((const fx4*)(src + 256 + 4 * lane));
            *(fx4*)(raw + 256 + 4 * lane) = v1;
        }
    }
    wave_sync();

    const int f    = lane & 31;
    const int half = lane >> 5;

    // ---- 2. shared pass: mean (half 0) and linear-decay/return (half 1) ----
    float meanf = 0.f;
    {
        float sum = 0.f, ldacc = 0.f, first = 0.f, last = 0.f;
        #pragma unroll
        for (int s = 0; s < S; ++s) {
            float v = raw[s * F + f];
            sum += v;
            ldacc += (float)(s + 1) * v;
            if (s == 0)     first = v;
            if (s == S - 1) last  = v;
        }
        if (half == 0) {
            meanf = sum * (1.0f / (float)S);
            stage[F + f] = meanf;                 // mean parked here; becomes z later
        } else {
            stage[2 * F + f] = ldacc * (1.0f / 55.0f);   // linspace(1,10)/55
            float ret = (first == 0.0f) ? 0.0f : last * fast_rcp(first);  // divide_no_nan
            stage[3 * F + f] = ret - 1.0f;
        }
    }
    wave_sync();

    // ---- 3. mean-subtract in place ----
    {
        float mf = stage[F + f];
        #pragma unroll
        for (int k = 0; k < 5; ++k) {
            int idx = lane + 64 * k;     // idx % 32 == f
            raw[idx] -= mf;
        }
    }
    wave_sync();

    // ---- 4. variance/std/z (half 0 lanes) ----
    if (half == 0) {
        float ss = 0.f;
        #pragma unroll
        for (int s = 0; s < S; ++s) {
            float d = raw[s * F + f];
            ss += d * d;
        }
        float var = ss * (1.0f / (float)S);             // biased variance
        float sd  = __builtin_amdgcn_sqrtf(var);
        stage[f]     = sd;
        stage[F + f] = (sd == 0.0f) ? 0.0f : meanf * fast_rcp(sd);  // z, overwrites mean
    }
    wave_sync();

    // ---- 5. pairwise products: 32x32 = 8x8 lane grid of 4x4 register tiles ----
    {
        const int rb = lane >> 3;   // 0..7
        const int cb = lane & 7;    // 0..7
        float acc[4][4];
        #pragma unroll
        for (int i = 0; i < 4; ++i)
            #pragma unroll
            for (int j = 0; j < 4; ++j) acc[i][j] = 0.f;

        #pragma unroll
        for (int s = 0; s < S; ++s) {
            fx4 a4 = *(fx4*)(raw + s * F + 4 * rb);   // 8 unique addrs -> broadcast
            fx4 b4 = *(fx4*)(raw + s * F + 4 * cb);
            const float aa[4] = {a4.x, a4.y, a4.z, a4.w};
            const float bb[4] = {b4.x, b4.y, b4.z, b4.w};
            #pragma unroll
            for (int i = 0; i < 4; ++i)
                #pragma unroll
                for (int j = 0; j < 4; ++j)
                    acc[i][j] += aa[i] * bb[j];
        }

        fx4 sa4 = *(fx4*)(stage + 4 * rb);   // std
        fx4 sb4 = *(fx4*)(stage + 4 * cb);
        const float sa[4] = {sa4.x, sa4.y, sa4.z, sa4.w};
        const float sb[4] = {sb4.x, sb4.y, sb4.z, sb4.w};

        #pragma unroll
        for (int i = 0; i < 4; ++i) {
            const int r = 4 * rb + i;
            #pragma unroll
            for (int j = 0; j < 4; ++j) {
                const int c = 4 * cb + j;
                if (r > c) {                       // strict lower triangle
                    const int p = (r * (r - 1)) / 2 + c;
                    float prod = acc[i][j];
                    stage[4 * F + p] = prod * (1.0f / 9.0f);   // cov: /(S-1)
                    float den = sa[i] * sb[j];
                    stage[4 * F + NPAIR + p] = (den == 0.0f) ? 0.0f
                                               : prod * (1.0f / (float)S) * fast_rcp(den);
                }
            }
        }
    }
    wave_sync();

    // ---- 6. coalesced streamed writeout: 280 float4 per stride ----
    {
        float* dst = out + (size_t)sid * OUTW;
        #pragma unroll
        for (int k = 0; k < 5; ++k) {
            int idx4 = lane + 64 * k;
            if (idx4 < OUTW / 4) {
                fx4 v = *(fx4*)(stage + 4 * idx4);
                __builtin_nontemporal_store(v, (fx4*)(dst + 4 * idx4));
            }
        }
    }
}

extern "C" void kernel_launch(void* const* d_in, const int* in_sizes, int n_in,
                              void* d_out, int out_size, void* d_ws, size_t ws_size,
                              hipStream_t stream)
{
    const float* in = (const float*)d_in[0];
    float* out      = (float*)d_out;
    const int nstrides = in_sizes[0] / (S * F);          // 122880 for (2048,600,32)
    const int grid     = (nstrides + WAVES - 1) / WAVES; // 30720
    fe_kernel<<<grid, 256, 0, stream>>>(in, out, nstrides);
}

// Round 4
// 144.289 us; speedup vs baseline: 1.2245x; 1.0406x over previous
//
#include <hip/hip_runtime.h>

// FeatureExpansion: per (b, ol) stride of 10x32 f32 -> 1120 f32 outputs
// [std(32) | z(32) | ld(32) | ret(32) | covf(496) | corrf(496)]
// One wave per stride; 4 waves per block; wave-local sync only.
// LDS-instruction-minimized: E[xy]-mu*mu trick removes mean-subtract and
// variance passes; single fused 10-read stats pass.

typedef float fx4 __attribute__((ext_vector_type(4)));

constexpr int S      = 10;
constexpr int F      = 32;
constexpr int NPAIR  = 496;     // F*(F-1)/2
constexpr int OUTW   = 1120;    // 4*F + 2*NPAIR
constexpr int WAVES  = 4;
// per-wave LDS slice (floats): raw[320] | mu[32] | rs[32] | stage[1120]
constexpr int SLICE  = 320 + 64 + OUTW;   // 1504 floats = 6016 B

// Wave-local barrier (each wave touches only its own LDS slice).
__device__ __forceinline__ void wave_sync() {
    asm volatile("s_waitcnt lgkmcnt(0)" ::: "memory");
    __builtin_amdgcn_sched_barrier(0);
}
__device__ __forceinline__ float fast_rcp(float x) { return __builtin_amdgcn_rcpf(x); }

__global__ __launch_bounds__(256, 4)
void fe_kernel(const float* __restrict__ in, float* __restrict__ out, int nstrides)
{
    __shared__ float lds[WAVES * SLICE];

    const int wv   = threadIdx.x >> 6;
    const int lane = threadIdx.x & 63;
    int sid = blockIdx.x * WAVES + wv;
    if (sid >= nstrides) sid = nstrides - 1;   // grid divides exactly for this shape

    float* raw   = &lds[wv * SLICE];   // 10x32 raw tile
    float* muv   = raw + 320;          // mean per feature
    float* rsv   = raw + 352;          // rcp(std) per feature (0 where std==0)
    float* stage = raw + 384;          // 1120 packed outputs

    const float* src = in + (size_t)sid * (S * F);

    // ---- P1: global -> LDS (2 vector loads, coalesced, streamed) ----
    {
        fx4 v0 = __builtin_nontemporal_load((const fx4*)(src + 4 * lane));
        *(fx4*)(raw + 4 * lane) = v0;
        if (lane < 16) {
            fx4 v1 = __builtin_nontemporal_load((const fx4*)(src + 256 + 4 * lane));
            *(fx4*)(raw + 256 + 4 * lane) = v1;
        }
    }
    wave_sync();

    const int f    = lane & 31;
    const int half = lane >> 5;

    // ---- P2: ONE 10-read pass -> mean, var (E[x^2]-mu^2), std, z, ld, ret ----
    {
        float sum = 0.f, sumsq = 0.f, ldacc = 0.f, first = 0.f, last = 0.f;
        #pragma unroll
        for (int s = 0; s < S; ++s) {
            float v = raw[s * F + f];          // lane l and l+32: same addr (broadcast)
            sum   += v;
            sumsq += v * v;
            ldacc += (float)(s + 1) * v;
            if (s == 0)     first = v;
            if (s == S - 1) last  = v;
        }
        if (half == 0) {
            float mean = sum * 0.1f;
            float var  = fmaxf(sumsq * 0.1f - mean * mean, 0.0f);  // biased var, guard cancellation
            float sd   = __builtin_amdgcn_sqrtf(var);
            float rs   = (sd == 0.0f) ? 0.0f : fast_rcp(sd);
            muv[f] = mean;
            rsv[f] = rs;
            stage[f]     = sd;                // std
            stage[F + f] = mean * rs;         // z = divide_no_nan(mean, std)
        } else {
            stage[2 * F + f] = ldacc * (1.0f / 55.0f);                // linspace(1,10)/55
            float ret = (first == 0.0f) ? 0.0f : last * fast_rcp(first);
            stage[3 * F + f] = ret - 1.0f;
        }
    }
    wave_sync();

    // ---- P5: pairwise products on RAW data; acc init = -10*mu_r*mu_c ----
    {
        const int rb = lane >> 3;   // 0..7
        const int cb = lane & 7;    // 0..7
        fx4 ma = *(fx4*)(muv + 4 * rb);
        fx4 mb = *(fx4*)(muv + 4 * cb);
        fx4 ra = *(fx4*)(rsv + 4 * rb);
        fx4 rc = *(fx4*)(rsv + 4 * cb);
        const float maa[4] = {ma.x, ma.y, ma.z, ma.w};
        const float mbb[4] = {mb.x, mb.y, mb.z, mb.w};
        const float raa[4] = {ra.x, ra.y, ra.z, ra.w};
        const float rcc[4] = {rc.x, rc.y, rc.z, rc.w};

        float acc[4][4];
        float nm[4];
        #pragma unroll
        for (int i = 0; i < 4; ++i) nm[i] = -10.0f * maa[i];
        #pragma unroll
        for (int i = 0; i < 4; ++i)
            #pragma unroll
            for (int j = 0; j < 4; ++j) acc[i][j] = nm[i] * mbb[j];

        #pragma unroll
        for (int s = 0; s < S; ++s) {
            fx4 a4 = *(fx4*)(raw + s * F + 4 * rb);   // 8 distinct addrs -> broadcast
            fx4 b4 = *(fx4*)(raw + s * F + 4 * cb);
            const float aa[4] = {a4.x, a4.y, a4.z, a4.w};
            const float bb[4] = {b4.x, b4.y, b4.z, b4.w};
            #pragma unroll
            for (int i = 0; i < 4; ++i)
                #pragma unroll
                for (int j = 0; j < 4; ++j)
                    acc[i][j] += aa[i] * bb[j];
        }

        #pragma unroll
        for (int i = 0; i < 4; ++i) {
            const int r = 4 * rb + i;
            #pragma unroll
            for (int j = 0; j < 4; ++j) {
                const int c = 4 * cb + j;
                if (r > c) {                        // strict lower triangle
                    const int p = (r * (r - 1)) / 2 + c;
                    float prod = acc[i][j];
                    stage[4 * F + p]         = prod * (1.0f / 9.0f);          // cov
                    stage[4 * F + NPAIR + p] = prod * 0.1f * raa[i] * rcc[j]; // corr
                }
            }
        }
    }
    wave_sync();

    // ---- P6: coalesced streamed writeout: 280 float4 per stride ----
    {
        float* dst = out + (size_t)sid * OUTW;
        #pragma unroll
        for (int k = 0; k < 5; ++k) {
            int idx4 = lane + 64 * k;
            if (idx4 < OUTW / 4) {
                fx4 v = *(fx4*)(stage + 4 * idx4);
                __builtin_nontemporal_store(v, (fx4*)(dst + 4 * idx4));
            }
        }
    }
}

extern "C" void kernel_launch(void* const* d_in, const int* in_sizes, int n_in,
                              void* d_out, int out_size, void* d_ws, size_t ws_size,
                              hipStream_t stream)
{
    const float* in = (const float*)d_in[0];
    float* out      = (float*)d_out;
    const int nstrides = in_sizes[0] / (S * F);          // 122880
    const int grid     = (nstrides + WAVES - 1) / WAVES; // 30720
    fe_kernel<<<grid, 256, 0, stream>>>(in, out, nstrides);
}